// Round 1
// baseline (129.694 us; speedup 1.0000x reference)
//
#include <hip/hip_runtime.h>
#include <hip/hip_bf16.h>

typedef __attribute__((ext_vector_type(8))) short v8s;
typedef __attribute__((ext_vector_type(4))) float v4f;

#define BB 2
#define TT 2048
#define HH 16
#define DD 64
#define QTILE 64
#define KVT 32

// round-to-nearest-even f32 -> bf16 bits
__device__ __forceinline__ unsigned short f2bf(float f) {
    unsigned int u = __builtin_bit_cast(unsigned int, f);
    u = u + 0x7FFFu + ((u >> 16) & 1u);
    return (unsigned short)(u >> 16);
}

__device__ __forceinline__ v8s pack8(unsigned long long lo, unsigned long long hi) {
    union { v8s v; unsigned long long q[2]; } u;
    u.q[0] = lo; u.q[1] = hi;
    return u.v;
}

__global__ __launch_bounds__(256)
void attn_fwd(const float* __restrict__ qg, const float* __restrict__ kvg,
              float* __restrict__ outg) {
    // K tile row-major [32][64] bf16, padded to 68 cols to spread banks
    __shared__ __align__(16) unsigned short Klds[KVT][68];
    // V tile transposed [d][s] bf16, padded to 36 cols
    __shared__ __align__(16) unsigned short Vt[DD][36];

    const int wg    = blockIdx.x;
    const int qtile = wg & 31;          // 2048/64 = 32 q-tiles
    const int h     = (wg >> 5) & 15;
    const int b     = wg >> 9;
    const int tid   = threadIdx.x;
    const int lane  = tid & 63;
    const int wid   = tid >> 6;
    const int lr    = lane & 15;        // MFMA row/col index
    const int lg    = lane >> 4;        // 0..3

    const int q0 = qtile * QTILE + wid * 16;   // this wave's first q row

    // ---- load Q fragments (held in regs), pre-scaled by 1/sqrt(d) * log2(e) ----
    const float qscale = 0.125f * 1.4426950408889634f;
    v8s qf[2];
    {
        const float* qb = qg + ((size_t)((b * TT + q0 + lr) * HH + h)) * DD;
        #pragma unroll
        for (int c = 0; c < 2; ++c) {
            float4 lo = *(const float4*)(qb + 32 * c + 4 * lg);
            float4 hi = *(const float4*)(qb + 32 * c + 4 * lg + 16);
            v8s f;
            f[0] = (short)f2bf(lo.x * qscale);
            f[1] = (short)f2bf(lo.y * qscale);
            f[2] = (short)f2bf(lo.z * qscale);
            f[3] = (short)f2bf(lo.w * qscale);
            f[4] = (short)f2bf(hi.x * qscale);
            f[5] = (short)f2bf(hi.y * qscale);
            f[6] = (short)f2bf(hi.z * qscale);
            f[7] = (short)f2bf(hi.w * qscale);
            qf[c] = f;
        }
    }

    v4f oa[4];
    #pragma unroll
    for (int dc = 0; dc < 4; ++dc)
        #pragma unroll
        for (int r = 0; r < 4; ++r) oa[dc][r] = 0.0f;
    float m = -INFINITY, lsum = 0.0f;

    for (int kv0 = 0; kv0 < TT; kv0 += KVT) {
        __syncthreads();
        // ---- stage K tile [32][64] fp32 -> bf16 LDS (coalesced float4 reads) ----
        #pragma unroll
        for (int i = 0; i < 2; ++i) {
            int id  = tid + 256 * i;
            int row = id >> 4;             // 0..31
            int cg  = (id & 15) * 4;       // 0..60
            const float* gp = kvg + ((size_t)(((b * TT + kv0 + row) * 2 + 0) * HH + h)) * DD + cg;
            float4 f = *(const float4*)gp;
            ushort4 w;
            w.x = f2bf(f.x); w.y = f2bf(f.y); w.z = f2bf(f.z); w.w = f2bf(f.w);
            *(ushort4*)&Klds[row][cg] = w;
        }
        // ---- stage V tile transposed: Vt[d][s] ----
        {
            int s0 = tid >> 4;             // 0..15 -> rows 2s0, 2s0+1
            int dg = (tid & 15) * 4;       // 0..60
            const float* gp0 = kvg + ((size_t)(((b * TT + kv0 + 2 * s0) * 2 + 1) * HH + h)) * DD + dg;
            const float* gp1 = gp0 + 2 * HH * DD;
            float4 fa = *(const float4*)gp0;
            float4 fb = *(const float4*)gp1;
            float av[4] = {fa.x, fa.y, fa.z, fa.w};
            float bv[4] = {fb.x, fb.y, fb.z, fb.w};
            #pragma unroll
            for (int i = 0; i < 4; ++i) {
                ushort2 w;
                w.x = f2bf(av[i]);
                w.y = f2bf(bv[i]);
                *(ushort2*)&Vt[dg + i][2 * s0] = w;
            }
        }
        __syncthreads();

        // ---- QK^T (swapped: D = K * Q^T), K-dim = d split into 2x32 ----
        v4f st0, st1;
        #pragma unroll
        for (int r = 0; r < 4; ++r) { st0[r] = 0.0f; st1[r] = 0.0f; }
        #pragma unroll
        for (int c = 0; c < 2; ++c) {
            {
                unsigned long long lo = *(const unsigned long long*)&Klds[lr][32 * c + 4 * lg];
                unsigned long long hi = *(const unsigned long long*)&Klds[lr][32 * c + 4 * lg + 16];
                st0 = __builtin_amdgcn_mfma_f32_16x16x32_bf16(pack8(lo, hi), qf[c], st0, 0, 0, 0);
            }
            {
                unsigned long long lo = *(const unsigned long long*)&Klds[16 + lr][32 * c + 4 * lg];
                unsigned long long hi = *(const unsigned long long*)&Klds[16 + lr][32 * c + 4 * lg + 16];
                st1 = __builtin_amdgcn_mfma_f32_16x16x32_bf16(pack8(lo, hi), qf[c], st1, 0, 0, 0);
            }
        }

        // ---- online softmax: lane holds 8 scores (kv pos 4lg+r, +16) of q-row q0+lr ----
        float sc[8] = {st0[0], st0[1], st0[2], st0[3], st1[0], st1[1], st1[2], st1[3]};
        float mc = sc[0];
        #pragma unroll
        for (int i = 1; i < 8; ++i) mc = fmaxf(mc, sc[i]);
        mc = fmaxf(mc, __shfl_xor(mc, 16));
        mc = fmaxf(mc, __shfl_xor(mc, 32));
        float mnew  = fmaxf(m, mc);
        float alpha = exp2f(m - mnew);
        float p[8], ps = 0.0f;
        #pragma unroll
        for (int i = 0; i < 8; ++i) { p[i] = exp2f(sc[i] - mnew); ps += p[i]; }
        ps += __shfl_xor(ps, 16);
        ps += __shfl_xor(ps, 32);
        lsum = lsum * alpha + ps;
        m = mnew;

        // rescale O accumulator (C-layout rows 4lg+r need alpha of that q-row)
        float ar0 = __shfl(alpha, 4 * lg + 0);
        float ar1 = __shfl(alpha, 4 * lg + 1);
        float ar2 = __shfl(alpha, 4 * lg + 2);
        float ar3 = __shfl(alpha, 4 * lg + 3);
        #pragma unroll
        for (int dc = 0; dc < 4; ++dc) {
            oa[dc][0] *= ar0; oa[dc][1] *= ar1; oa[dc][2] *= ar2; oa[dc][3] *= ar3;
        }

        // ---- P fragment (A-operand slot j <-> kv pos 16*(j>>2)+4lg+(j&3)) ----
        v8s pf;
        #pragma unroll
        for (int i = 0; i < 8; ++i) pf[i] = (short)f2bf(p[i]);

        // ---- PV: O += P * V, one 32-k MFMA per 16-d chunk ----
        #pragma unroll
        for (int dc = 0; dc < 4; ++dc) {
            unsigned long long lo = *(const unsigned long long*)&Vt[16 * dc + lr][4 * lg];
            unsigned long long hi = *(const unsigned long long*)&Vt[16 * dc + lr][4 * lg + 16];
            oa[dc] = __builtin_amdgcn_mfma_f32_16x16x32_bf16(pf, pack8(lo, hi), oa[dc], 0, 0, 0);
        }
    }

    // ---- epilogue: divide by lsum (per q-row) and store fp32 ----
    float rl  = 1.0f / lsum;
    float rr0 = __shfl(rl, 4 * lg + 0);
    float rr1 = __shfl(rl, 4 * lg + 1);
    float rr2 = __shfl(rl, 4 * lg + 2);
    float rr3 = __shfl(rl, 4 * lg + 3);
    #pragma unroll
    for (int dc = 0; dc < 4; ++dc) {
        size_t base = ((size_t)((b * TT + q0) * HH + h)) * DD + 16 * dc + lr;
        outg[base + (size_t)(4 * lg + 0) * HH * DD] = oa[dc][0] * rr0;
        outg[base + (size_t)(4 * lg + 1) * HH * DD] = oa[dc][1] * rr1;
        outg[base + (size_t)(4 * lg + 2) * HH * DD] = oa[dc][2] * rr2;
        outg[base + (size_t)(4 * lg + 3) * HH * DD] = oa[dc][3] * rr3;
    }
}

extern "C" void kernel_launch(void* const* d_in, const int* in_sizes, int n_in,
                              void* d_out, int out_size, void* d_ws, size_t ws_size,
                              hipStream_t stream) {
    const float* q  = (const float*)d_in[0];
    const float* kv = (const float*)d_in[1];
    float* out      = (float*)d_out;
    dim3 grid(BB * HH * (TT / QTILE));   // 2*16*32 = 1024
    dim3 block(256);
    hipLaunchKernelGGL(attn_fwd, grid, block, 0, stream, q, kv, out);
}

// Round 3
// 94.256 us; speedup vs baseline: 1.3760x; 1.3760x over previous
//
#include <hip/hip_runtime.h>
#include <hip/hip_bf16.h>

typedef __attribute__((ext_vector_type(8))) short v8s;
typedef __attribute__((ext_vector_type(4))) float v4f;
typedef unsigned long long u64;
typedef unsigned short u16;

#define BB 2
#define TT 2048
#define HH 16
#define DD 64

// ---------- helpers ----------

__device__ __forceinline__ unsigned short f2bf(float f) {
    unsigned int u = __builtin_bit_cast(unsigned int, f);
    u = u + 0x7FFFu + ((u >> 16) & 1u);
    return (unsigned short)(u >> 16);
}

__device__ __forceinline__ unsigned cvt2(float a, float b) {
    return ((unsigned)f2bf(b) << 16) | (unsigned)f2bf(a);
}

__device__ __forceinline__ v8s cvt8s(const float4& lo, const float4& hi, float s) {
    union { v8s v; unsigned u[4]; } r;
    r.u[0] = cvt2(lo.x * s, lo.y * s);
    r.u[1] = cvt2(lo.z * s, lo.w * s);
    r.u[2] = cvt2(hi.x * s, hi.y * s);
    r.u[3] = cvt2(hi.z * s, hi.w * s);
    return r.v;
}

__device__ __forceinline__ v8s pack8(u64 lo, u64 hi) {
    union { v8s v; u64 q[2]; } u;
    u.q[0] = lo; u.q[1] = hi;
    return u.v;
}

typedef __attribute__((address_space(1))) const unsigned int gas_u32;
typedef __attribute__((address_space(3))) unsigned int las_u32;
__device__ __forceinline__ void gl_lds16(const void* g, void* l) {
    __builtin_amdgcn_global_load_lds((gas_u32*)g, (las_u32*)l, 16, 0, 0);
}

// swizzled byte offset within one 64x64 bf16 tile (row stride 128B,
// 16B blocks XORed by row&7; read granules of 8B stay contiguous)
__device__ __forceinline__ int tl_addr(int row, int col) {
    return row * 128 + ((((col >> 3) ^ (row & 7)) << 4) | ((col & 7) << 1));
}

// ---------- pre-pass: fp32 KV -> bf16 swizzled K tiles + V^T tiles ----------

__global__ __launch_bounds__(256)
void prep_kv(const float* __restrict__ kvg, u16* __restrict__ wsK, u16* __restrict__ wsV) {
    __shared__ u16 vlds[64][72];
    const int wg   = blockIdx.x;
    const int tile = wg & 31;
    const int h    = (wg >> 5) & 15;
    const int b    = wg >> 9;
    const int t    = threadIdx.x;
    const int s0   = tile * 64;

    u16* kout = wsK + (((size_t)(b * 16 + h) * 32 + tile) * 4096);
    u16* vout = wsV + (((size_t)(b * 16 + h) * 32 + tile) * 4096);

    #pragma unroll
    for (int i = 0; i < 2; ++i) {
        int id  = t + 256 * i;
        int row = id >> 3;        // 0..63 (kv position within tile)
        int d8  = id & 7;         // 16B block (8 d-elements)
        const float* kp = kvg + ((((size_t)(b * TT + s0 + row) * 2 + 0) * HH + h) * DD + 8 * d8);
        const float* vp = kvg + ((((size_t)(b * TT + s0 + row) * 2 + 1) * HH + h) * DD + 8 * d8);
        float4 ka = *(const float4*)kp;
        float4 kb = *(const float4*)(kp + 4);
        float4 va = *(const float4*)vp;
        float4 vb = *(const float4*)(vp + 4);
        // K: direct swizzled store (row-major [s][d])
        *(v8s*)((char*)kout + row * 128 + ((d8 ^ (row & 7)) << 4)) = cvt8s(ka, kb, 1.0f);
        // V: to LDS for transpose
        *(v8s*)&vlds[row][8 * d8] = cvt8s(va, vb, 1.0f);
    }
    __syncthreads();
    #pragma unroll
    for (int i = 0; i < 2; ++i) {
        int id = t + 256 * i;
        int dd = id >> 3;         // d row of V^T
        int s8 = id & 7;          // 16B block (8 s-elements)
        union { v8s v; u16 w[8]; } r;
        #pragma unroll
        for (int j = 0; j < 8; ++j) r.w[j] = vlds[8 * s8 + j][dd];
        *(v8s*)((char*)vout + dd * 128 + ((s8 ^ (dd & 7)) << 4)) = r.v;
    }
}

// ---------- attention v2: bf16 tiles via global_load_lds, KVT=64, 8 waves ----------

__global__ __launch_bounds__(512, 4)
void attn_v2(const float* __restrict__ qg, const u16* __restrict__ wsK,
             const u16* __restrict__ wsV, float* __restrict__ outg) {
    __shared__ __align__(16) u16 KT[2][4096];
    __shared__ __align__(16) u16 VT[2][4096];

    const int bid  = blockIdx.x;
    const int wgid = (bid & 7) * 64 + (bid >> 3);   // XCD-contiguous (512 % 8 == 0)
    const int qt   = wgid & 15;
    const int h    = (wgid >> 4) & 15;
    const int b    = wgid >> 8;
    const int tid  = threadIdx.x;
    const int lane = tid & 63;
    const int wid  = tid >> 6;
    const int lr   = lane & 15;
    const int lg   = lane >> 4;
    const int wb   = wid << 9;                       // wave-uniform LDS base (shorts)

    const u16* kbase = wsK + (size_t)(b * 16 + h) * 131072;
    const u16* vbase = wsV + (size_t)(b * 16 + h) * 131072;

    const int q0 = qt * 128 + wid * 16;

    // Q fragments (pre-scaled into exp2 domain)
    const float qscale = 0.125f * 1.4426950408889634f;
    v8s qf[2];
    {
        const float* qb = qg + ((size_t)((b * TT + q0 + lr) * HH + h)) * DD;
        #pragma unroll
        for (int c = 0; c < 2; ++c) {
            float4 lo = *(const float4*)(qb + 32 * c + 4 * lg);
            float4 hi = *(const float4*)(qb + 32 * c + 4 * lg + 16);
            qf[c] = cvt8s(lo, hi, qscale);
        }
    }

    // prologue: stage tile 0
    gl_lds16(kbase + tid * 8, &KT[0][0] + wb);
    gl_lds16(vbase + tid * 8, &VT[0][0] + wb);

    v4f oa[4];
    #pragma unroll
    for (int dc = 0; dc < 4; ++dc)
        #pragma unroll
        for (int r = 0; r < 4; ++r) oa[dc][r] = 0.0f;
    float m = -INFINITY, lsum = 0.0f;

    for (int t = 0; t < 32; ++t) {
        const int cur = t & 1;
        if (t < 31) {
            gl_lds16(kbase + (t + 1) * 4096 + tid * 8, &KT[cur ^ 1][0] + wb);
            gl_lds16(vbase + (t + 1) * 4096 + tid * 8, &VT[cur ^ 1][0] + wb);
            asm volatile("s_waitcnt vmcnt(2)" ::: "memory");
        } else {
            asm volatile("s_waitcnt vmcnt(0)" ::: "memory");
        }
        __builtin_amdgcn_s_barrier();

        const char* kb = (const char*)&KT[cur][0];
        const char* vb = (const char*)&VT[cur][0];

        // ---- QK^T (swapped): st[rb] rows = kv 16rb+4lg+r, cols = q lr ----
        v4f st[4];
        #pragma unroll
        for (int rb = 0; rb < 4; ++rb)
            #pragma unroll
            for (int r = 0; r < 4; ++r) st[rb][r] = 0.0f;
        __builtin_amdgcn_s_setprio(1);
        #pragma unroll
        for (int c = 0; c < 2; ++c) {
            #pragma unroll
            for (int rb = 0; rb < 4; ++rb) {
                int row = 16 * rb + lr;
                int d0  = 32 * c + 4 * lg;
                u64 lo = *(const u64*)(kb + tl_addr(row, d0));
                u64 hi = *(const u64*)(kb + tl_addr(row, d0 + 16));
                st[rb] = __builtin_amdgcn_mfma_f32_16x16x32_bf16(pack8(lo, hi), qf[c], st[rb], 0, 0, 0);
            }
        }
        __builtin_amdgcn_s_setprio(0);

        // ---- online softmax over 64 kv, defer-max (THR=8 in log2 units) ----
        float mc = st[0][0];
        #pragma unroll
        for (int rb = 0; rb < 4; ++rb)
            #pragma unroll
            for (int r = 0; r < 4; ++r) mc = fmaxf(mc, st[rb][r]);
        mc = fmaxf(mc, __shfl_xor(mc, 16));
        mc = fmaxf(mc, __shfl_xor(mc, 32));
        if (!__all(mc - m <= 8.0f)) {
            float mnew  = fmaxf(m, mc);
            float alpha = __builtin_amdgcn_exp2f(m - mnew);
            lsum *= alpha;
            m = mnew;
            float a0 = __shfl(alpha, 4 * lg + 0);
            float a1 = __shfl(alpha, 4 * lg + 1);
            float a2 = __shfl(alpha, 4 * lg + 2);
            float a3 = __shfl(alpha, 4 * lg + 3);
            #pragma unroll
            for (int dc = 0; dc < 4; ++dc) {
                oa[dc][0] *= a0; oa[dc][1] *= a1; oa[dc][2] *= a2; oa[dc][3] *= a3;
            }
        }
        float p[16], ps = 0.0f;
        #pragma unroll
        for (int rb = 0; rb < 4; ++rb)
            #pragma unroll
            for (int r = 0; r < 4; ++r) {
                float e = __builtin_amdgcn_exp2f(st[rb][r] - m);
                p[4 * rb + r] = e; ps += e;
            }
        ps += __shfl_xor(ps, 16);
        ps += __shfl_xor(ps, 32);
        lsum += ps;

        // ---- P -> bf16 fragments (slot j of pf[ks] <-> p[8ks + j]) ----
        v8s pf[2];
        #pragma unroll
        for (int ks = 0; ks < 2; ++ks) {
            union { v8s v; unsigned u[4]; } r;
            r.u[0] = cvt2(p[8 * ks + 0], p[8 * ks + 1]);
            r.u[1] = cvt2(p[8 * ks + 2], p[8 * ks + 3]);
            r.u[2] = cvt2(p[8 * ks + 4], p[8 * ks + 5]);
            r.u[3] = cvt2(p[8 * ks + 6], p[8 * ks + 7]);
            pf[ks] = r.v;
        }

        // ---- PV: O += P * V ----
        __builtin_amdgcn_s_setprio(1);
        #pragma unroll
        for (int ks = 0; ks < 2; ++ks) {
            #pragma unroll
            for (int dc = 0; dc < 4; ++dc) {
                int d  = 16 * dc + lr;
                int s0 = 32 * ks + 4 * lg;
                u64 lo = *(const u64*)(vb + tl_addr(d, s0));
                u64 hi = *(const u64*)(vb + tl_addr(d, s0 + 16));
                oa[dc] = __builtin_amdgcn_mfma_f32_16x16x32_bf16(pf[ks], pack8(lo, hi), oa[dc], 0, 0, 0);
            }
        }
        __builtin_amdgcn_s_setprio(0);

        __builtin_amdgcn_s_barrier();
    }

    // ---- epilogue ----
    float rl = 1.0f / lsum;
    float r0 = __shfl(rl, 4 * lg + 0);
    float r1 = __shfl(rl, 4 * lg + 1);
    float r2 = __shfl(rl, 4 * lg + 2);
    float r3 = __shfl(rl, 4 * lg + 3);
    #pragma unroll
    for (int dc = 0; dc < 4; ++dc) {
        size_t base = ((size_t)((b * TT + q0) * HH + h)) * DD + 16 * dc + lr;
        outg[base + (size_t)(4 * lg + 0) * HH * DD] = oa[dc][0] * r0;
        outg[base + (size_t)(4 * lg + 1) * HH * DD] = oa[dc][1] * r1;
        outg[base + (size_t)(4 * lg + 2) * HH * DD] = oa[dc][2] * r2;
        outg[base + (size_t)(4 * lg + 3) * HH * DD] = oa[dc][3] * r3;
    }
}

// ---------- fallback v1 (proven) ----------

__global__ __launch_bounds__(256)
void attn_fwd_v1(const float* __restrict__ qg, const float* __restrict__ kvg,
                 float* __restrict__ outg) {
    __shared__ __align__(16) u16 Klds[32][68];
    __shared__ __align__(16) u16 Vt[DD][36];

    const int wg    = blockIdx.x;
    const int qtile = wg & 31;
    const int h     = (wg >> 5) & 15;
    const int b     = wg >> 9;
    const int tid   = threadIdx.x;
    const int lane  = tid & 63;
    const int wid   = tid >> 6;
    const int lr    = lane & 15;
    const int lg    = lane >> 4;
    const int q0    = qtile * 64 + wid * 16;

    const float qscale = 0.125f * 1.4426950408889634f;
    v8s qf[2];
    {
        const float* qb = qg + ((size_t)((b * TT + q0 + lr) * HH + h)) * DD;
        #pragma unroll
        for (int c = 0; c < 2; ++c) {
            float4 lo = *(const float4*)(qb + 32 * c + 4 * lg);
            float4 hi = *(const float4*)(qb + 32 * c + 4 * lg + 16);
            qf[c] = cvt8s(lo, hi, qscale);
        }
    }

    v4f oa[4];
    #pragma unroll
    for (int dc = 0; dc < 4; ++dc)
        #pragma unroll
        for (int r = 0; r < 4; ++r) oa[dc][r] = 0.0f;
    float m = -INFINITY, lsum = 0.0f;

    for (int kv0 = 0; kv0 < TT; kv0 += 32) {
        __syncthreads();
        #pragma unroll
        for (int i = 0; i < 2; ++i) {
            int id  = tid + 256 * i;
            int row = id >> 4;
            int cg  = (id & 15) * 4;
            const float* gp = kvg + ((size_t)(((b * TT + kv0 + row) * 2 + 0) * HH + h)) * DD + cg;
            float4 f = *(const float4*)gp;
            ushort4 w;
            w.x = f2bf(f.x); w.y = f2bf(f.y); w.z = f2bf(f.z); w.w = f2bf(f.w);
            *(ushort4*)&Klds[row][cg] = w;
        }
        {
            int s0 = tid >> 4;
            int dg = (tid & 15) * 4;
            const float* gp0 = kvg + ((size_t)(((b * TT + kv0 + 2 * s0) * 2 + 1) * HH + h)) * DD + dg;
            const float* gp1 = gp0 + 2 * HH * DD;
            float4 fa = *(const float4*)gp0;
            float4 fb = *(const float4*)gp1;
            float av[4] = {fa.x, fa.y, fa.z, fa.w};
            float bv[4] = {fb.x, fb.y, fb.z, fb.w};
            #pragma unroll
            for (int i = 0; i < 4; ++i) {
                ushort2 w;
                w.x = f2bf(av[i]);
                w.y = f2bf(bv[i]);
                *(ushort2*)&Vt[dg + i][2 * s0] = w;
            }
        }
        __syncthreads();

        v4f st0, st1;
        #pragma unroll
        for (int r = 0; r < 4; ++r) { st0[r] = 0.0f; st1[r] = 0.0f; }
        #pragma unroll
        for (int c = 0; c < 2; ++c) {
            {
                u64 lo = *(const u64*)&Klds[lr][32 * c + 4 * lg];
                u64 hi = *(const u64*)&Klds[lr][32 * c + 4 * lg + 16];
                st0 = __builtin_amdgcn_mfma_f32_16x16x32_bf16(pack8(lo, hi), qf[c], st0, 0, 0, 0);
            }
            {
                u64 lo = *(const u64*)&Klds[16 + lr][32 * c + 4 * lg];
                u64 hi = *(const u64*)&Klds[16 + lr][32 * c + 4 * lg + 16];
                st1 = __builtin_amdgcn_mfma_f32_16x16x32_bf16(pack8(lo, hi), qf[c], st1, 0, 0, 0);
            }
        }

        float sc[8] = {st0[0], st0[1], st0[2], st0[3], st1[0], st1[1], st1[2], st1[3]};
        float mc = sc[0];
        #pragma unroll
        for (int i = 1; i < 8; ++i) mc = fmaxf(mc, sc[i]);
        mc = fmaxf(mc, __shfl_xor(mc, 16));
        mc = fmaxf(mc, __shfl_xor(mc, 32));
        float mnew  = fmaxf(m, mc);
        float alpha = __builtin_amdgcn_exp2f(m - mnew);
        float p[8], ps = 0.0f;
        #pragma unroll
        for (int i = 0; i < 8; ++i) { p[i] = __builtin_amdgcn_exp2f(sc[i] - mnew); ps += p[i]; }
        ps += __shfl_xor(ps, 16);
        ps += __shfl_xor(ps, 32);
        lsum = lsum * alpha + ps;
        m = mnew;

        float ar0 = __shfl(alpha, 4 * lg + 0);
        float ar1 = __shfl(alpha, 4 * lg + 1);
        float ar2 = __shfl(alpha, 4 * lg + 2);
        float ar3 = __shfl(alpha, 4 * lg + 3);
        #pragma unroll
        for (int dc = 0; dc < 4; ++dc) {
            oa[dc][0] *= ar0; oa[dc][1] *= ar1; oa[dc][2] *= ar2; oa[dc][3] *= ar3;
        }

        v8s pf;
        #pragma unroll
        for (int i = 0; i < 8; ++i) pf[i] = (short)f2bf(p[i]);

        #pragma unroll
        for (int dc = 0; dc < 4; ++dc) {
            u64 lo = *(const u64*)&Vt[16 * dc + lr][4 * lg];
            u64 hi = *(const u64*)&Vt[16 * dc + lr][4 * lg + 16];
            oa[dc] = __builtin_amdgcn_mfma_f32_16x16x32_bf16(pf, pack8(lo, hi), oa[dc], 0, 0, 0);
        }
    }

    float rl  = 1.0f / lsum;
    float rr0 = __shfl(rl, 4 * lg + 0);
    float rr1 = __shfl(rl, 4 * lg + 1);
    float rr2 = __shfl(rl, 4 * lg + 2);
    float rr3 = __shfl(rl, 4 * lg + 3);
    #pragma unroll
    for (int dc = 0; dc < 4; ++dc) {
        size_t base = ((size_t)((b * TT + q0) * HH + h)) * DD + 16 * dc + lr;
        outg[base + (size_t)(4 * lg + 0) * HH * DD] = oa[dc][0] * rr0;
        outg[base + (size_t)(4 * lg + 1) * HH * DD] = oa[dc][1] * rr1;
        outg[base + (size_t)(4 * lg + 2) * HH * DD] = oa[dc][2] * rr2;
        outg[base + (size_t)(4 * lg + 3) * HH * DD] = oa[dc][3] * rr3;
    }
}

extern "C" void kernel_launch(void* const* d_in, const int* in_sizes, int n_in,
                              void* d_out, int out_size, void* d_ws, size_t ws_size,
                              hipStream_t stream) {
    const float* q  = (const float*)d_in[0];
    const float* kv = (const float*)d_in[1];
    float* out      = (float*)d_out;
    if (ws_size >= (size_t)16777216) {
        u16* wsK = (u16*)d_ws;
        u16* wsV = wsK + 4194304;
        hipLaunchKernelGGL(prep_kv, dim3(BB * HH * 32), dim3(256), 0, stream, kv, wsK, wsV);
        hipLaunchKernelGGL(attn_v2, dim3(512), dim3(512), 0, stream, q, wsK, wsV, out);
    } else {
        hipLaunchKernelGGL(attn_fwd_v1, dim3(1024), dim3(256), 0, stream, q, kv, out);
    }
}

// Round 4
// 69.006 us; speedup vs baseline: 1.8795x; 1.3659x over previous
//
#include <hip/hip_runtime.h>
#include <hip/hip_bf16.h>

typedef __attribute__((ext_vector_type(8))) short v8s;
typedef __attribute__((ext_vector_type(4))) float v4f;
typedef unsigned long long u64;
typedef unsigned short u16;

#define BB 2
#define TT 2048
#define HH 16
#define DD 64

// ---------- helpers ----------

__device__ __forceinline__ unsigned short f2bf(float f) {
    unsigned int u = __builtin_bit_cast(unsigned int, f);
    u = u + 0x7FFFu + ((u >> 16) & 1u);
    return (unsigned short)(u >> 16);
}

__device__ __forceinline__ unsigned cvt2(float a, float b) {
    return ((unsigned)f2bf(b) << 16) | (unsigned)f2bf(a);
}

__device__ __forceinline__ v8s cvt8s(const float4& lo, const float4& hi, float s) {
    union { v8s v; unsigned u[4]; } r;
    r.u[0] = cvt2(lo.x * s, lo.y * s);
    r.u[1] = cvt2(lo.z * s, lo.w * s);
    r.u[2] = cvt2(hi.x * s, hi.y * s);
    r.u[3] = cvt2(hi.z * s, hi.w * s);
    return r.v;
}

// packed f32x2 -> bf16x2 (RNE), S0 -> lo, S1 -> hi
__device__ __forceinline__ unsigned cvtpk(float lo, float hi) {
    unsigned r;
    asm("v_cvt_pk_bf16_f32 %0, %1, %2" : "=v"(r) : "v"(lo), "v"(hi));
    return r;
}

__device__ __forceinline__ v8s pack8(u64 lo, u64 hi) {
    union { v8s v; u64 q[2]; } u;
    u.q[0] = lo; u.q[1] = hi;
    return u.v;
}

typedef __attribute__((address_space(1))) const unsigned int gas_u32;
typedef __attribute__((address_space(3))) unsigned int las_u32;
__device__ __forceinline__ void gl_lds16(const void* g, void* l) {
    __builtin_amdgcn_global_load_lds((gas_u32*)g, (las_u32*)l, 16, 0, 0);
}

// ---------- pre-pass: fp32 KV -> fragment-ordered bf16 K / V^T tile images ----
// K image: 16B block (row s, bi) at byte  s*128 + ((bi ^ (s&7))<<4),
//   contents K[s][32c+4lg+{0..3}], K[s][32c+16+4lg+{0..3}]  (c=bi>>2, lg=bi&3)
// V image: 16B block (row d, bi) at byte  d*128 + ((bi ^ (d&7))<<4),
//   contents V[32ks+4lg+{0..3}][d], V[32ks+16+4lg+{0..3}][d] (ks=bi>>2, lg=bi&3)

__global__ __launch_bounds__(256)
void prep_kv(const float* __restrict__ kvg, u16* __restrict__ wsK, u16* __restrict__ wsV) {
    __shared__ u16 vlds[64][72];
    const int wg   = blockIdx.x;
    const int tile = wg & 31;
    const int h    = (wg >> 5) & 15;
    const int b    = wg >> 9;
    const int t    = threadIdx.x;
    const int s0   = tile * 64;

    u16* kout = wsK + (((size_t)(b * 16 + h) * 32 + tile) * 4096);
    u16* vout = wsV + (((size_t)(b * 16 + h) * 32 + tile) * 4096);

    // K: fragment blocks straight from global
    #pragma unroll
    for (int i = 0; i < 2; ++i) {
        int id  = t + 256 * i;
        int row = id >> 3;          // kv position in tile
        int bi  = id & 7;
        int c   = bi >> 2, lg = bi & 3;
        const float* kp = kvg + ((((size_t)(b * TT + s0 + row) * 2 + 0) * HH + h) * DD + 32 * c + 4 * lg);
        float4 ka = *(const float4*)kp;
        float4 kb = *(const float4*)(kp + 16);
        *(v8s*)((char*)kout + row * 128 + ((bi ^ (row & 7)) << 4)) = cvt8s(ka, kb, 1.0f);
    }
    // V rows -> LDS (row-major) for transpose
    #pragma unroll
    for (int i = 0; i < 2; ++i) {
        int id  = t + 256 * i;
        int row = id >> 3;
        int d8  = id & 7;
        const float* vp = kvg + ((((size_t)(b * TT + s0 + row) * 2 + 1) * HH + h) * DD + 8 * d8);
        float4 va = *(const float4*)vp;
        float4 vb = *(const float4*)(vp + 4);
        *(v8s*)&vlds[row][8 * d8] = cvt8s(va, vb, 1.0f);
    }
    __syncthreads();
    // V^T fragment blocks gathered from LDS
    #pragma unroll
    for (int i = 0; i < 2; ++i) {
        int id = t + 256 * i;
        int dd = id >> 3;
        int bi = id & 7;
        int ks = bi >> 2, lg = bi & 3;
        union { v8s v; u16 w[8]; } r;
        #pragma unroll
        for (int j = 0; j < 4; ++j) {
            r.w[j]     = vlds[32 * ks + 4 * lg + j][dd];
            r.w[4 + j] = vlds[32 * ks + 16 + 4 * lg + j][dd];
        }
        *(v8s*)((char*)vout + dd * 128 + ((bi ^ (dd & 7)) << 4)) = r.v;
    }
}

// ---------- attention v3: 4 waves x 32 q-rows, b128 fragment reads ----------

__global__ __launch_bounds__(256, 2)
void attn_v3(const float* __restrict__ qg, const u16* __restrict__ wsK,
             const u16* __restrict__ wsV, float* __restrict__ outg) {
    __shared__ __align__(16) u16 KT[2][4096];
    __shared__ __align__(16) u16 VT[2][4096];

    const int bid  = blockIdx.x;
    const int wgid = (bid & 7) * 64 + (bid >> 3);   // XCD-contiguous (512 % 8 == 0)
    const int qt   = wgid & 15;
    const int h    = (wgid >> 4) & 15;
    const int b    = wgid >> 8;
    const int tid  = threadIdx.x;
    const int lane = tid & 63;
    const int wid  = tid >> 6;
    const int lr   = lane & 15;
    const int lg   = lane >> 4;

    const u16* kbase = wsK + (size_t)(b * 16 + h) * 131072;
    const u16* vbase = wsV + (size_t)(b * 16 + h) * 131072;

    const int q0 = qt * 128 + wid * 32;

    // Q fragments (pre-scaled into exp2 domain): qf[qc][c]
    const float qscale = 0.125f * 1.4426950408889634f;
    v8s qf[2][2];
    #pragma unroll
    for (int qc = 0; qc < 2; ++qc) {
        const float* qb = qg + ((size_t)((b * TT + q0 + 16 * qc + lr) * HH + h)) * DD;
        #pragma unroll
        for (int c = 0; c < 2; ++c) {
            float4 lo = *(const float4*)(qb + 32 * c + 4 * lg);
            float4 hi = *(const float4*)(qb + 32 * c + 4 * lg + 16);
            qf[qc][c] = cvt8s(lo, hi, qscale);
        }
    }

#define STAGE(buf, tt)                                                                 \
    do {                                                                               \
        gl_lds16(kbase + (size_t)(tt) * 4096 + tid * 8,        (char*)&KT[buf][0] + wid * 1024);          \
        gl_lds16(kbase + (size_t)(tt) * 4096 + 2048 + tid * 8, (char*)&KT[buf][0] + 4096 + wid * 1024);   \
        gl_lds16(vbase + (size_t)(tt) * 4096 + tid * 8,        (char*)&VT[buf][0] + wid * 1024);          \
        gl_lds16(vbase + (size_t)(tt) * 4096 + 2048 + tid * 8, (char*)&VT[buf][0] + 4096 + wid * 1024);   \
    } while (0)

    STAGE(0, 0);

    v4f oa[2][4];
    #pragma unroll
    for (int qc = 0; qc < 2; ++qc)
        #pragma unroll
        for (int dc = 0; dc < 4; ++dc)
            #pragma unroll
            for (int r = 0; r < 4; ++r) oa[qc][dc][r] = 0.0f;
    float m[2]    = {-INFINITY, -INFINITY};
    float lsum[2] = {0.0f, 0.0f};

    for (int t = 0; t < 32; ++t) {
        const int cur = t & 1;
        if (t < 31) {
            STAGE(cur ^ 1, t + 1);
            asm volatile("s_waitcnt vmcnt(4)" ::: "memory");
        } else {
            asm volatile("s_waitcnt vmcnt(0)" ::: "memory");
        }
        __builtin_amdgcn_s_barrier();

        const char* kb = (const char*)&KT[cur][0];
        const char* vb = (const char*)&VT[cur][0];

        // ---- QK^T (swapped): st[qc][rb] rows = kv 16rb+4lg+r, cols = q 16qc+lr ----
        v4f st[2][4];
        #pragma unroll
        for (int qc = 0; qc < 2; ++qc)
            #pragma unroll
            for (int rb = 0; rb < 4; ++rb)
                #pragma unroll
                for (int r = 0; r < 4; ++r) st[qc][rb][r] = 0.0f;
        __builtin_amdgcn_s_setprio(1);
        #pragma unroll
        for (int c = 0; c < 2; ++c) {
            #pragma unroll
            for (int rb = 0; rb < 4; ++rb) {
                int s = 16 * rb + lr;
                v8s kf = *(const v8s*)(kb + s * 128 + (((4 * c + lg) ^ (s & 7)) << 4));
                st[0][rb] = __builtin_amdgcn_mfma_f32_16x16x32_bf16(kf, qf[0][c], st[0][rb], 0, 0, 0);
                st[1][rb] = __builtin_amdgcn_mfma_f32_16x16x32_bf16(kf, qf[1][c], st[1][rb], 0, 0, 0);
            }
        }
        __builtin_amdgcn_s_setprio(0);

        // ---- online softmax per qc, defer-max (THR=8 in log2 units) ----
        float mc[2];
        #pragma unroll
        for (int qc = 0; qc < 2; ++qc) {
            float v = st[qc][0][0];
            #pragma unroll
            for (int rb = 0; rb < 4; ++rb)
                #pragma unroll
                for (int r = 0; r < 4; ++r) v = fmaxf(v, st[qc][rb][r]);
            v = fmaxf(v, __shfl_xor(v, 16));
            v = fmaxf(v, __shfl_xor(v, 32));
            mc[qc] = v;
        }
        bool trig = (mc[0] - m[0] > 8.0f) || (mc[1] - m[1] > 8.0f);
        if (__any(trig)) {
            #pragma unroll
            for (int qc = 0; qc < 2; ++qc) {
                float mnew  = fmaxf(m[qc], mc[qc]);
                float alpha = __builtin_amdgcn_exp2f(m[qc] - mnew);
                lsum[qc] *= alpha;
                m[qc] = mnew;
                float a0 = __shfl(alpha, 4 * lg + 0);
                float a1 = __shfl(alpha, 4 * lg + 1);
                float a2 = __shfl(alpha, 4 * lg + 2);
                float a3 = __shfl(alpha, 4 * lg + 3);
                #pragma unroll
                for (int dc = 0; dc < 4; ++dc) {
                    oa[qc][dc][0] *= a0; oa[qc][dc][1] *= a1;
                    oa[qc][dc][2] *= a2; oa[qc][dc][3] *= a3;
                }
            }
        }
        #pragma unroll
        for (int qc = 0; qc < 2; ++qc) {
            float ps = 0.0f;
            #pragma unroll
            for (int rb = 0; rb < 4; ++rb)
                #pragma unroll
                for (int r = 0; r < 4; ++r) {
                    float e = __builtin_amdgcn_exp2f(st[qc][rb][r] - m[qc]);
                    st[qc][rb][r] = e;
                    ps += e;
                }
            ps += __shfl_xor(ps, 16);
            ps += __shfl_xor(ps, 32);
            lsum[qc] += ps;
        }

        // ---- P -> bf16 fragments via v_cvt_pk_bf16_f32 ----
        v8s pf[2][2];
        #pragma unroll
        for (int qc = 0; qc < 2; ++qc)
            #pragma unroll
            for (int ks = 0; ks < 2; ++ks) {
                union { v8s v; unsigned u[4]; } r;
                r.u[0] = cvtpk(st[qc][2 * ks][0],     st[qc][2 * ks][1]);
                r.u[1] = cvtpk(st[qc][2 * ks][2],     st[qc][2 * ks][3]);
                r.u[2] = cvtpk(st[qc][2 * ks + 1][0], st[qc][2 * ks + 1][1]);
                r.u[3] = cvtpk(st[qc][2 * ks + 1][2], st[qc][2 * ks + 1][3]);
                pf[qc][ks] = r.v;
            }

        // ---- PV: O += P * V ----
        __builtin_amdgcn_s_setprio(1);
        #pragma unroll
        for (int ks = 0; ks < 2; ++ks) {
            #pragma unroll
            for (int dc = 0; dc < 4; ++dc) {
                int d = 16 * dc + lr;
                v8s vf = *(const v8s*)(vb + d * 128 + (((4 * ks + lg) ^ (d & 7)) << 4));
                oa[0][dc] = __builtin_amdgcn_mfma_f32_16x16x32_bf16(pf[0][ks], vf, oa[0][dc], 0, 0, 0);
                oa[1][dc] = __builtin_amdgcn_mfma_f32_16x16x32_bf16(pf[1][ks], vf, oa[1][dc], 0, 0, 0);
            }
        }
        __builtin_amdgcn_s_setprio(0);

        __builtin_amdgcn_s_barrier();
    }

    // ---- epilogue: divide by lsum (per q-row) and store fp32 ----
    #pragma unroll
    for (int qc = 0; qc < 2; ++qc) {
        float rl = 1.0f / lsum[qc];
        float r0 = __shfl(rl, 4 * lg + 0);
        float r1 = __shfl(rl, 4 * lg + 1);
        float r2 = __shfl(rl, 4 * lg + 2);
        float r3 = __shfl(rl, 4 * lg + 3);
        #pragma unroll
        for (int dc = 0; dc < 4; ++dc) {
            size_t base = ((size_t)((b * TT + q0 + 16 * qc) * HH + h)) * DD + 16 * dc + lr;
            outg[base + (size_t)(4 * lg + 0) * HH * DD] = oa[qc][dc][0] * r0;
            outg[base + (size_t)(4 * lg + 1) * HH * DD] = oa[qc][dc][1] * r1;
            outg[base + (size_t)(4 * lg + 2) * HH * DD] = oa[qc][dc][2] * r2;
            outg[base + (size_t)(4 * lg + 3) * HH * DD] = oa[qc][dc][3] * r3;
        }
    }
}

// ---------- fallback v1 (proven) ----------

__global__ __launch_bounds__(256)
void attn_fwd_v1(const float* __restrict__ qg, const float* __restrict__ kvg,
                 float* __restrict__ outg) {
    __shared__ __align__(16) u16 Klds[32][68];
    __shared__ __align__(16) u16 Vt[DD][36];

    const int wg    = blockIdx.x;
    const int qtile = wg & 31;
    const int h     = (wg >> 5) & 15;
    const int b     = wg >> 9;
    const int tid   = threadIdx.x;
    const int lane  = tid & 63;
    const int wid   = tid >> 6;
    const int lr    = lane & 15;
    const int lg    = lane >> 4;
    const int q0    = qtile * 64 + wid * 16;

    const float qscale = 0.125f * 1.4426950408889634f;
    v8s qf[2];
    {
        const float* qb = qg + ((size_t)((b * TT + q0 + lr) * HH + h)) * DD;
        #pragma unroll
        for (int c = 0; c < 2; ++c) {
            float4 lo = *(const float4*)(qb + 32 * c + 4 * lg);
            float4 hi = *(const float4*)(qb + 32 * c + 4 * lg + 16);
            qf[c] = cvt8s(lo, hi, qscale);
        }
    }

    v4f oa[4];
    #pragma unroll
    for (int dc = 0; dc < 4; ++dc)
        #pragma unroll
        for (int r = 0; r < 4; ++r) oa[dc][r] = 0.0f;
    float m = -INFINITY, lsum = 0.0f;

    for (int kv0 = 0; kv0 < TT; kv0 += 32) {
        __syncthreads();
        #pragma unroll
        for (int i = 0; i < 2; ++i) {
            int id  = tid + 256 * i;
            int row = id >> 4;
            int cg  = (id & 15) * 4;
            const float* gp = kvg + ((size_t)(((b * TT + kv0 + row) * 2 + 0) * HH + h)) * DD + cg;
            float4 f = *(const float4*)gp;
            ushort4 w;
            w.x = f2bf(f.x); w.y = f2bf(f.y); w.z = f2bf(f.z); w.w = f2bf(f.w);
            *(ushort4*)&Klds[row][cg] = w;
        }
        {
            int s0 = tid >> 4;
            int dg = (tid & 15) * 4;
            const float* gp0 = kvg + ((size_t)(((b * TT + kv0 + 2 * s0) * 2 + 1) * HH + h)) * DD + dg;
            const float* gp1 = gp0 + 2 * HH * DD;
            float4 fa = *(const float4*)gp0;
            float4 fb = *(const float4*)gp1;
            float av[4] = {fa.x, fa.y, fa.z, fa.w};
            float bv[4] = {fb.x, fb.y, fb.z, fb.w};
            #pragma unroll
            for (int i = 0; i < 4; ++i) {
                ushort2 w;
                w.x = f2bf(av[i]);
                w.y = f2bf(bv[i]);
                *(ushort2*)&Vt[dg + i][2 * s0] = w;
            }
        }
        __syncthreads();

        v4f st0, st1;
        #pragma unroll
        for (int r = 0; r < 4; ++r) { st0[r] = 0.0f; st1[r] = 0.0f; }
        #pragma unroll
        for (int c = 0; c < 2; ++c) {
            {
                u64 lo = *(const u64*)&Klds[lr][32 * c + 4 * lg];
                u64 hi = *(const u64*)&Klds[lr][32 * c + 4 * lg + 16];
                st0 = __builtin_amdgcn_mfma_f32_16x16x32_bf16(pack8(lo, hi), qf[c], st0, 0, 0, 0);
            }
            {
                u64 lo = *(const u64*)&Klds[16 + lr][32 * c + 4 * lg];
                u64 hi = *(const u64*)&Klds[16 + lr][32 * c + 4 * lg + 16];
                st1 = __builtin_amdgcn_mfma_f32_16x16x32_bf16(pack8(lo, hi), qf[c], st1, 0, 0, 0);
            }
        }

        float sc[8] = {st0[0], st0[1], st0[2], st0[3], st1[0], st1[1], st1[2], st1[3]};
        float mc = sc[0];
        #pragma unroll
        for (int i = 1; i < 8; ++i) mc = fmaxf(mc, sc[i]);
        mc = fmaxf(mc, __shfl_xor(mc, 16));
        mc = fmaxf(mc, __shfl_xor(mc, 32));
        float mnew  = fmaxf(m, mc);
        float alpha = __builtin_amdgcn_exp2f(m - mnew);
        float p[8], ps = 0.0f;
        #pragma unroll
        for (int i = 0; i < 8; ++i) { p[i] = __builtin_amdgcn_exp2f(sc[i] - mnew); ps += p[i]; }
        ps += __shfl_xor(ps, 16);
        ps += __shfl_xor(ps, 32);
        lsum = lsum * alpha + ps;
        m = mnew;

        float ar0 = __shfl(alpha, 4 * lg + 0);
        float ar1 = __shfl(alpha, 4 * lg + 1);
        float ar2 = __shfl(alpha, 4 * lg + 2);
        float ar3 = __shfl(alpha, 4 * lg + 3);
        #pragma unroll
        for (int dc = 0; dc < 4; ++dc) {
            oa[dc][0] *= ar0; oa[dc][1] *= ar1; oa[dc][2] *= ar2; oa[dc][3] *= ar3;
        }

        v8s pf;
        #pragma unroll
        for (int i = 0; i < 8; ++i) pf[i] = (short)f2bf(p[i]);

        #pragma unroll
        for (int dc = 0; dc < 4; ++dc) {
            u64 lo = *(const u64*)&Vt[16 * dc + lr][4 * lg];
            u64 hi = *(const u64*)&Vt[16 * dc + lr][4 * lg + 16];
            oa[dc] = __builtin_amdgcn_mfma_f32_16x16x32_bf16(pf, pack8(lo, hi), oa[dc], 0, 0, 0);
        }
    }

    float rl  = 1.0f / lsum;
    float rr0 = __shfl(rl, 4 * lg + 0);
    float rr1 = __shfl(rl, 4 * lg + 1);
    float rr2 = __shfl(rl, 4 * lg + 2);
    float rr3 = __shfl(rl, 4 * lg + 3);
    #pragma unroll
    for (int dc = 0; dc < 4; ++dc) {
        size_t base = ((size_t)((b * TT + q0) * HH + h)) * DD + 16 * dc + lr;
        outg[base + (size_t)(4 * lg + 0) * HH * DD] = oa[dc][0] * rr0;
        outg[base + (size_t)(4 * lg + 1) * HH * DD] = oa[dc][1] * rr1;
        outg[base + (size_t)(4 * lg + 2) * HH * DD] = oa[dc][2] * rr2;
        outg[base + (size_t)(4 * lg + 3) * HH * DD] = oa[dc][3] * rr3;
    }
}

extern "C" void kernel_launch(void* const* d_in, const int* in_sizes, int n_in,
                              void* d_out, int out_size, void* d_ws, size_t ws_size,
                              hipStream_t stream) {
    const float* q  = (const float*)d_in[0];
    const float* kv = (const float*)d_in[1];
    float* out      = (float*)d_out;
    if (ws_size >= (size_t)16777216) {
        u16* wsK = (u16*)d_ws;
        u16* wsV = wsK + 4194304;
        hipLaunchKernelGGL(prep_kv, dim3(BB * HH * 32), dim3(256), 0, stream, kv, wsK, wsV);
        hipLaunchKernelGGL(attn_v3, dim3(512), dim3(256), 0, stream, q, wsK, wsV, out);
    } else {
        hipLaunchKernelGGL(attn_fwd_v1, dim3(1024), dim3(256), 0, stream, q, kv, out);
    }
}

// Round 5
// 65.510 us; speedup vs baseline: 1.9798x; 1.0534x over previous
//
#include <hip/hip_runtime.h>
#include <hip/hip_bf16.h>

typedef __attribute__((ext_vector_type(8))) short v8s;
typedef __attribute__((ext_vector_type(4))) float v4f;
typedef unsigned long long u64;
typedef unsigned short u16;

#define BB 2
#define TT 2048
#define HH 16
#define DD 64

// ---------- helpers ----------

__device__ __forceinline__ unsigned short f2bf(float f) {
    unsigned int u = __builtin_bit_cast(unsigned int, f);
    u = u + 0x7FFFu + ((u >> 16) & 1u);
    return (unsigned short)(u >> 16);
}

__device__ __forceinline__ unsigned cvt2(float a, float b) {
    return ((unsigned)f2bf(b) << 16) | (unsigned)f2bf(a);
}

__device__ __forceinline__ v8s cvt8s(const float4& lo, const float4& hi, float s) {
    union { v8s v; unsigned u[4]; } r;
    r.u[0] = cvt2(lo.x * s, lo.y * s);
    r.u[1] = cvt2(lo.z * s, lo.w * s);
    r.u[2] = cvt2(hi.x * s, hi.y * s);
    r.u[3] = cvt2(hi.z * s, hi.w * s);
    return r.v;
}

// packed f32x2 -> bf16x2 (RNE), S0 -> lo, S1 -> hi
__device__ __forceinline__ unsigned cvtpk(float lo, float hi) {
    unsigned r;
    asm("v_cvt_pk_bf16_f32 %0, %1, %2" : "=v"(r) : "v"(lo), "v"(hi));
    return r;
}

__device__ __forceinline__ v8s pack8(u64 lo, u64 hi) {
    union { v8s v; u64 q[2]; } u;
    u.q[0] = lo; u.q[1] = hi;
    return u.v;
}

typedef __attribute__((address_space(1))) const unsigned int gas_u32;
typedef __attribute__((address_space(3))) unsigned int las_u32;
__device__ __forceinline__ void gl_lds16(const void* g, void* l) {
    __builtin_amdgcn_global_load_lds((gas_u32*)g, (las_u32*)l, 16, 0, 0);
}

// ---------- pre-pass: fp32 KV -> fragment-ordered bf16 K / V^T tile images ----
// K image: 16B block (row s, bi) at byte  s*128 + ((bi ^ (s&7))<<4),
//   contents K[s][32c+4lg+{0..3}], K[s][32c+16+4lg+{0..3}]  (c=bi>>2, lg=bi&3)
// V image: 16B block (row d, bi) at byte  d*128 + ((bi ^ (d&7))<<4),
//   contents V[32ks+4lg+{0..3}][d], V[32ks+16+4lg+{0..3}][d] (ks=bi>>2, lg=bi&3)

__global__ __launch_bounds__(256)
void prep_kv(const float* __restrict__ kvg, u16* __restrict__ wsK, u16* __restrict__ wsV) {
    __shared__ u16 vlds[64][72];
    const int wg   = blockIdx.x;
    const int tile = wg & 31;
    const int h    = (wg >> 5) & 15;
    const int b    = wg >> 9;
    const int t    = threadIdx.x;
    const int s0   = tile * 64;

    u16* kout = wsK + (((size_t)(b * 16 + h) * 32 + tile) * 4096);
    u16* vout = wsV + (((size_t)(b * 16 + h) * 32 + tile) * 4096);

    // K: fragment blocks straight from global
    #pragma unroll
    for (int i = 0; i < 2; ++i) {
        int id  = t + 256 * i;
        int row = id >> 3;          // kv position in tile
        int bi  = id & 7;
        int c   = bi >> 2, lg = bi & 3;
        const float* kp = kvg + ((((size_t)(b * TT + s0 + row) * 2 + 0) * HH + h) * DD + 32 * c + 4 * lg);
        float4 ka = *(const float4*)kp;
        float4 kb = *(const float4*)(kp + 16);
        *(v8s*)((char*)kout + row * 128 + ((bi ^ (row & 7)) << 4)) = cvt8s(ka, kb, 1.0f);
    }
    // V rows -> LDS (row-major) for transpose
    #pragma unroll
    for (int i = 0; i < 2; ++i) {
        int id  = t + 256 * i;
        int row = id >> 3;
        int d8  = id & 7;
        const float* vp = kvg + ((((size_t)(b * TT + s0 + row) * 2 + 1) * HH + h) * DD + 8 * d8);
        float4 va = *(const float4*)vp;
        float4 vb = *(const float4*)(vp + 4);
        *(v8s*)&vlds[row][8 * d8] = cvt8s(va, vb, 1.0f);
    }
    __syncthreads();
    // V^T fragment blocks gathered from LDS
    #pragma unroll
    for (int i = 0; i < 2; ++i) {
        int id = t + 256 * i;
        int dd = id >> 3;
        int bi = id & 7;
        int ks = bi >> 2, lg = bi & 3;
        union { v8s v; u16 w[8]; } r;
        #pragma unroll
        for (int j = 0; j < 4; ++j) {
            r.w[j]     = vlds[32 * ks + 4 * lg + j][dd];
            r.w[4 + j] = vlds[32 * ks + 16 + 4 * lg + j][dd];
        }
        *(v8s*)((char*)vout + dd * 128 + ((bi ^ (dd & 7)) << 4)) = r.v;
    }
}

// ---------- attention v4: 8 waves x 16 q-rows, 16 waves/CU ----------

__global__ __launch_bounds__(512, 4)
void attn_v4(const float* __restrict__ qg, const u16* __restrict__ wsK,
             const u16* __restrict__ wsV, float* __restrict__ outg) {
    __shared__ __align__(16) u16 KT[2][4096];
    __shared__ __align__(16) u16 VT[2][4096];

    const int bid  = blockIdx.x;
    const int wgid = (bid & 7) * 64 + (bid >> 3);   // XCD-contiguous (512 % 8 == 0)
    const int qt   = wgid & 15;
    const int h    = (wgid >> 4) & 15;
    const int b    = wgid >> 8;
    const int tid  = threadIdx.x;
    const int lane = tid & 63;
    const int wid  = tid >> 6;
    const int lr   = lane & 15;
    const int lg   = lane >> 4;

    const u16* kbase = wsK + (size_t)(b * 16 + h) * 131072;
    const u16* vbase = wsV + (size_t)(b * 16 + h) * 131072;

    const int q0 = qt * 128 + wid * 16;

    // Q fragments (pre-scaled into exp2 domain)
    const float qscale = 0.125f * 1.4426950408889634f;
    v8s qf[2];
    {
        const float* qb = qg + ((size_t)((b * TT + q0 + lr) * HH + h)) * DD;
        #pragma unroll
        for (int c = 0; c < 2; ++c) {
            float4 lo = *(const float4*)(qb + 32 * c + 4 * lg);
            float4 hi = *(const float4*)(qb + 32 * c + 4 * lg + 16);
            qf[c] = cvt8s(lo, hi, qscale);
        }
    }

#define STAGE(buf, tt)                                                                        \
    do {                                                                                      \
        gl_lds16(kbase + (size_t)(tt) * 4096 + tid * 8, (char*)&KT[buf][0] + wid * 1024);     \
        gl_lds16(vbase + (size_t)(tt) * 4096 + tid * 8, (char*)&VT[buf][0] + wid * 1024);     \
    } while (0)

    STAGE(0, 0);

    v4f oa[4];
    #pragma unroll
    for (int dc = 0; dc < 4; ++dc)
        #pragma unroll
        for (int r = 0; r < 4; ++r) oa[dc][r] = 0.0f;
    float m = -INFINITY, lsum = 0.0f;

    for (int t = 0; t < 32; ++t) {
        const int cur = t & 1;
        if (t < 31) {
            STAGE(cur ^ 1, t + 1);
            asm volatile("s_waitcnt vmcnt(2)" ::: "memory");
        } else {
            asm volatile("s_waitcnt vmcnt(0)" ::: "memory");
        }
        __builtin_amdgcn_s_barrier();

        const char* kb = (const char*)&KT[cur][0];
        const char* vb = (const char*)&VT[cur][0];

        // ---- QK^T (swapped): st[rb] rows = kv 16rb+4lg+r, cols = q lr ----
        v4f st[4];
        #pragma unroll
        for (int rb = 0; rb < 4; ++rb)
            #pragma unroll
            for (int r = 0; r < 4; ++r) st[rb][r] = 0.0f;
        __builtin_amdgcn_s_setprio(1);
        #pragma unroll
        for (int c = 0; c < 2; ++c) {
            #pragma unroll
            for (int rb = 0; rb < 4; ++rb) {
                int s = 16 * rb + lr;
                v8s kf = *(const v8s*)(kb + s * 128 + (((4 * c + lg) ^ (s & 7)) << 4));
                st[rb] = __builtin_amdgcn_mfma_f32_16x16x32_bf16(kf, qf[c], st[rb], 0, 0, 0);
            }
        }
        __builtin_amdgcn_s_setprio(0);

        // ---- online softmax over 64 kv, defer-max (THR=8 in log2 units) ----
        float mc = st[0][0];
        #pragma unroll
        for (int rb = 0; rb < 4; ++rb)
            #pragma unroll
            for (int r = 0; r < 4; ++r) mc = fmaxf(mc, st[rb][r]);
        mc = fmaxf(mc, __shfl_xor(mc, 16));
        mc = fmaxf(mc, __shfl_xor(mc, 32));
        if (!__all(mc - m <= 8.0f)) {
            float mnew  = fmaxf(m, mc);
            float alpha = __builtin_amdgcn_exp2f(m - mnew);
            lsum *= alpha;
            m = mnew;
            float a0 = __shfl(alpha, 4 * lg + 0);
            float a1 = __shfl(alpha, 4 * lg + 1);
            float a2 = __shfl(alpha, 4 * lg + 2);
            float a3 = __shfl(alpha, 4 * lg + 3);
            #pragma unroll
            for (int dc = 0; dc < 4; ++dc) {
                oa[dc][0] *= a0; oa[dc][1] *= a1;
                oa[dc][2] *= a2; oa[dc][3] *= a3;
            }
        }
        float ps = 0.0f;
        #pragma unroll
        for (int rb = 0; rb < 4; ++rb)
            #pragma unroll
            for (int r = 0; r < 4; ++r) {
                float e = __builtin_amdgcn_exp2f(st[rb][r] - m);
                st[rb][r] = e;
                ps += e;
            }
        ps += __shfl_xor(ps, 16);
        ps += __shfl_xor(ps, 32);
        lsum += ps;

        // ---- P -> bf16 fragments via v_cvt_pk_bf16_f32 ----
        v8s pf[2];
        #pragma unroll
        for (int ks = 0; ks < 2; ++ks) {
            union { v8s v; unsigned u[4]; } r;
            r.u[0] = cvtpk(st[2 * ks][0],     st[2 * ks][1]);
            r.u[1] = cvtpk(st[2 * ks][2],     st[2 * ks][3]);
            r.u[2] = cvtpk(st[2 * ks + 1][0], st[2 * ks + 1][1]);
            r.u[3] = cvtpk(st[2 * ks + 1][2], st[2 * ks + 1][3]);
            pf[ks] = r.v;
        }

        // ---- PV: O += P * V ----
        __builtin_amdgcn_s_setprio(1);
        #pragma unroll
        for (int ks = 0; ks < 2; ++ks) {
            #pragma unroll
            for (int dc = 0; dc < 4; ++dc) {
                int d = 16 * dc + lr;
                v8s vf = *(const v8s*)(vb + d * 128 + (((4 * ks + lg) ^ (d & 7)) << 4));
                oa[dc] = __builtin_amdgcn_mfma_f32_16x16x32_bf16(pf[ks], vf, oa[dc], 0, 0, 0);
            }
        }
        __builtin_amdgcn_s_setprio(0);

        __builtin_amdgcn_s_barrier();
    }

    // ---- epilogue: divide by lsum (per q-row) and store fp32 ----
    float rl = 1.0f / lsum;
    float r0 = __shfl(rl, 4 * lg + 0);
    float r1 = __shfl(rl, 4 * lg + 1);
    float r2 = __shfl(rl, 4 * lg + 2);
    float r3 = __shfl(rl, 4 * lg + 3);
    #pragma unroll
    for (int dc = 0; dc < 4; ++dc) {
        size_t base = ((size_t)((b * TT + q0) * HH + h)) * DD + 16 * dc + lr;
        outg[base + (size_t)(4 * lg + 0) * HH * DD] = oa[dc][0] * r0;
        outg[base + (size_t)(4 * lg + 1) * HH * DD] = oa[dc][1] * r1;
        outg[base + (size_t)(4 * lg + 2) * HH * DD] = oa[dc][2] * r2;
        outg[base + (size_t)(4 * lg + 3) * HH * DD] = oa[dc][3] * r3;
    }
}

// ---------- fallback v1 (proven) ----------

__global__ __launch_bounds__(256)
void attn_fwd_v1(const float* __restrict__ qg, const float* __restrict__ kvg,
                 float* __restrict__ outg) {
    __shared__ __align__(16) u16 Klds[32][68];
    __shared__ __align__(16) u16 Vt[DD][36];

    const int wg    = blockIdx.x;
    const int qtile = wg & 31;
    const int h     = (wg >> 5) & 15;
    const int b     = wg >> 9;
    const int tid   = threadIdx.x;
    const int lane  = tid & 63;
    const int wid   = tid >> 6;
    const int lr    = lane & 15;
    const int lg    = lane >> 4;
    const int q0    = qtile * 64 + wid * 16;

    const float qscale = 0.125f * 1.4426950408889634f;
    v8s qf[2];
    {
        const float* qb = qg + ((size_t)((b * TT + q0 + lr) * HH + h)) * DD;
        #pragma unroll
        for (int c = 0; c < 2; ++c) {
            float4 lo = *(const float4*)(qb + 32 * c + 4 * lg);
            float4 hi = *(const float4*)(qb + 32 * c + 4 * lg + 16);
            qf[c] = cvt8s(lo, hi, qscale);
        }
    }

    v4f oa[4];
    #pragma unroll
    for (int dc = 0; dc < 4; ++dc)
        #pragma unroll
        for (int r = 0; r < 4; ++r) oa[dc][r] = 0.0f;
    float m = -INFINITY, lsum = 0.0f;

    for (int kv0 = 0; kv0 < TT; kv0 += 32) {
        __syncthreads();
        #pragma unroll
        for (int i = 0; i < 2; ++i) {
            int id  = tid + 256 * i;
            int row = id >> 4;
            int cg  = (id & 15) * 4;
            const float* gp = kvg + ((size_t)(((b * TT + kv0 + row) * 2 + 0) * HH + h)) * DD + cg;
            float4 f = *(const float4*)gp;
            ushort4 w;
            w.x = f2bf(f.x); w.y = f2bf(f.y); w.z = f2bf(f.z); w.w = f2bf(f.w);
            *(ushort4*)&Klds[row][cg] = w;
        }
        {
            int s0 = tid >> 4;
            int dg = (tid & 15) * 4;
            const float* gp0 = kvg + ((size_t)(((b * TT + kv0 + 2 * s0) * 2 + 1) * HH + h)) * DD + dg;
            const float* gp1 = gp0 + 2 * HH * DD;
            float4 fa = *(const float4*)gp0;
            float4 fb = *(const float4*)gp1;
            float av[4] = {fa.x, fa.y, fa.z, fa.w};
            float bv[4] = {fb.x, fb.y, fb.z, fb.w};
            #pragma unroll
            for (int i = 0; i < 4; ++i) {
                ushort2 w;
                w.x = f2bf(av[i]);
                w.y = f2bf(bv[i]);
                *(ushort2*)&Vt[dg + i][2 * s0] = w;
            }
        }
        __syncthreads();

        v4f st0, st1;
        #pragma unroll
        for (int r = 0; r < 4; ++r) { st0[r] = 0.0f; st1[r] = 0.0f; }
        #pragma unroll
        for (int c = 0; c < 2; ++c) {
            {
                u64 lo = *(const u64*)&Klds[lr][32 * c + 4 * lg];
                u64 hi = *(const u64*)&Klds[lr][32 * c + 4 * lg + 16];
                st0 = __builtin_amdgcn_mfma_f32_16x16x32_bf16(pack8(lo, hi), qf[c], st0, 0, 0, 0);
            }
            {
                u64 lo = *(const u64*)&Klds[16 + lr][32 * c + 4 * lg];
                u64 hi = *(const u64*)&Klds[16 + lr][32 * c + 4 * lg + 16];
                st1 = __builtin_amdgcn_mfma_f32_16x16x32_bf16(pack8(lo, hi), qf[c], st1, 0, 0, 0);
            }
        }

        float sc[8] = {st0[0], st0[1], st0[2], st0[3], st1[0], st1[1], st1[2], st1[3]};
        float mc = sc[0];
        #pragma unroll
        for (int i = 1; i < 8; ++i) mc = fmaxf(mc, sc[i]);
        mc = fmaxf(mc, __shfl_xor(mc, 16));
        mc = fmaxf(mc, __shfl_xor(mc, 32));
        float mnew  = fmaxf(m, mc);
        float alpha = __builtin_amdgcn_exp2f(m - mnew);
        float p[8], ps = 0.0f;
        #pragma unroll
        for (int i = 0; i < 8; ++i) { p[i] = __builtin_amdgcn_exp2f(sc[i] - mnew); ps += p[i]; }
        ps += __shfl_xor(ps, 16);
        ps += __shfl_xor(ps, 32);
        lsum = lsum * alpha + ps;
        m = mnew;

        float ar0 = __shfl(alpha, 4 * lg + 0);
        float ar1 = __shfl(alpha, 4 * lg + 1);
        float ar2 = __shfl(alpha, 4 * lg + 2);
        float ar3 = __shfl(alpha, 4 * lg + 3);
        #pragma unroll
        for (int dc = 0; dc < 4; ++dc) {
            oa[dc][0] *= ar0; oa[dc][1] *= ar1; oa[dc][2] *= ar2; oa[dc][3] *= ar3;
        }

        v8s pf;
        #pragma unroll
        for (int i = 0; i < 8; ++i) pf[i] = (short)f2bf(p[i]);

        #pragma unroll
        for (int dc = 0; dc < 4; ++dc) {
            u64 lo = *(const u64*)&Vt[16 * dc + lr][4 * lg];
            u64 hi = *(const u64*)&Vt[16 * dc + lr][4 * lg + 16];
            oa[dc] = __builtin_amdgcn_mfma_f32_16x16x32_bf16(pf, pack8(lo, hi), oa[dc], 0, 0, 0);
        }
    }

    float rl  = 1.0f / lsum;
    float rr0 = __shfl(rl, 4 * lg + 0);
    float rr1 = __shfl(rl, 4 * lg + 1);
    float rr2 = __shfl(rl, 4 * lg + 2);
    float rr3 = __shfl(rl, 4 * lg + 3);
    #pragma unroll
    for (int dc = 0; dc < 4; ++dc) {
        size_t base = ((size_t)((b * TT + q0) * HH + h)) * DD + 16 * dc + lr;
        outg[base + (size_t)(4 * lg + 0) * HH * DD] = oa[dc][0] * rr0;
        outg[base + (size_t)(4 * lg + 1) * HH * DD] = oa[dc][1] * rr1;
        outg[base + (size_t)(4 * lg + 2) * HH * DD] = oa[dc][2] * rr2;
        outg[base + (size_t)(4 * lg + 3) * HH * DD] = oa[dc][3] * rr3;
    }
}

extern "C" void kernel_launch(void* const* d_in, const int* in_sizes, int n_in,
                              void* d_out, int out_size, void* d_ws, size_t ws_size,
                              hipStream_t stream) {
    const float* q  = (const float*)d_in[0];
    const float* kv = (const float*)d_in[1];
    float* out      = (float*)d_out;
    if (ws_size >= (size_t)16777216) {
        u16* wsK = (u16*)d_ws;
        u16* wsV = wsK + 4194304;
        hipLaunchKernelGGL(prep_kv, dim3(BB * HH * 32), dim3(256), 0, stream, kv, wsK, wsV);
        hipLaunchKernelGGL(attn_v4, dim3(512), dim3(512), 0, stream, q, wsK, wsV, out);
    } else {
        hipLaunchKernelGGL(attn_fwd_v1, dim3(1024), dim3(256), 0, stream, q, kv, out);
    }
}

// Round 7
// 65.032 us; speedup vs baseline: 1.9943x; 1.0073x over previous
//
#include <hip/hip_runtime.h>
#include <hip/hip_bf16.h>

typedef __attribute__((ext_vector_type(8)))  short v8s;
typedef __attribute__((ext_vector_type(4)))  float v4f;
typedef __attribute__((ext_vector_type(16))) float v16f;
typedef unsigned long long u64;
typedef unsigned short u16;

#define BB 2
#define TT 2048
#define HH 16
#define DD 64

// ---------- helpers ----------

__device__ __forceinline__ unsigned short f2bf(float f) {
    unsigned int u = __builtin_bit_cast(unsigned int, f);
    u = u + 0x7FFFu + ((u >> 16) & 1u);
    return (unsigned short)(u >> 16);
}

__device__ __forceinline__ unsigned cvt2(float a, float b) {
    return ((unsigned)f2bf(b) << 16) | (unsigned)f2bf(a);
}

__device__ __forceinline__ v8s cvt8s(const float4& lo, const float4& hi, float s) {
    union { v8s v; unsigned u[4]; } r;
    r.u[0] = cvt2(lo.x * s, lo.y * s);
    r.u[1] = cvt2(lo.z * s, lo.w * s);
    r.u[2] = cvt2(hi.x * s, hi.y * s);
    r.u[3] = cvt2(hi.z * s, hi.w * s);
    return r.v;
}

// packed f32x2 -> bf16x2 (RNE), S0 -> lo, S1 -> hi
__device__ __forceinline__ unsigned cvtpk(float lo, float hi) {
    unsigned r;
    asm("v_cvt_pk_bf16_f32 %0, %1, %2" : "=v"(r) : "v"(lo), "v"(hi));
    return r;
}

__device__ __forceinline__ v8s pack8(u64 lo, u64 hi) {
    union { v8s v; u64 q[2]; } u;
    u.q[0] = lo; u.q[1] = hi;
    return u.v;
}

typedef __attribute__((address_space(1))) const unsigned int gas_u32;
typedef __attribute__((address_space(3))) unsigned int las_u32;
__device__ __forceinline__ void gl_lds16(const void* g, void* l) {
    __builtin_amdgcn_global_load_lds((gas_u32*)g, (las_u32*)l, 16, 0, 0);
}

// ---------- pre-pass: fragment-ordered images for 32x32x16 MFMA ----------
// k-slot map M(j,h): value (j&3) + 8*(j>>2) + 4h within each 16-chunk.
// K image: row s (0..63), block bi = 2c + h at byte s*128 + ((bi^(s&7))<<4),
//   contents {K[s][16c+4h+0..3], K[s][16c+8+4h+0..3]}
// V image: row d (0..63), block bi = 2cc + h at byte d*128 + ((bi^(d&7))<<4),
//   contents {V[16cc+4h+0..3][d], V[16cc+8+4h+0..3][d]}

__global__ __launch_bounds__(256)
void prep_kv(const float* __restrict__ kvg, u16* __restrict__ wsK, u16* __restrict__ wsV) {
    __shared__ u16 vlds[64][72];
    const int wg   = blockIdx.x;
    const int tile = wg & 31;
    const int h    = (wg >> 5) & 15;
    const int b    = wg >> 9;
    const int t    = threadIdx.x;
    const int s0   = tile * 64;

    u16* kout = wsK + (((size_t)(b * 16 + h) * 32 + tile) * 4096);
    u16* vout = wsV + (((size_t)(b * 16 + h) * 32 + tile) * 4096);

    // K fragment blocks straight from global
    #pragma unroll
    for (int i = 0; i < 2; ++i) {
        int id  = t + 256 * i;
        int row = id >> 3;          // kv position in tile
        int bi  = id & 7;
        int c   = bi >> 1, hh = bi & 1;
        const float* kp = kvg + ((((size_t)(b * TT + s0 + row) * 2 + 0) * HH + h) * DD + 16 * c + 4 * hh);
        float4 ka = *(const float4*)kp;
        float4 kb = *(const float4*)(kp + 8);
        *(v8s*)((char*)kout + row * 128 + ((bi ^ (row & 7)) << 4)) = cvt8s(ka, kb, 1.0f);
    }
    // V rows -> LDS (row-major) for transpose
    #pragma unroll
    for (int i = 0; i < 2; ++i) {
        int id  = t + 256 * i;
        int row = id >> 3;
        int d8  = id & 7;
        const float* vp = kvg + ((((size_t)(b * TT + s0 + row) * 2 + 1) * HH + h) * DD + 8 * d8);
        float4 va = *(const float4*)vp;
        float4 vb = *(const float4*)(vp + 4);
        *(v8s*)&vlds[row][8 * d8] = cvt8s(va, vb, 1.0f);
    }
    __syncthreads();
    // V^T fragment blocks gathered from LDS
    #pragma unroll
    for (int i = 0; i < 2; ++i) {
        int id = t + 256 * i;
        int dd = id >> 3;
        int bi = id & 7;
        int cc = bi >> 1, hh = bi & 1;
        union { v8s v; u16 w[8]; } r;
        #pragma unroll
        for (int j = 0; j < 4; ++j) {
            r.w[j]     = vlds[16 * cc + 4 * hh + j][dd];
            r.w[4 + j] = vlds[16 * cc + 8 + 4 * hh + j][dd];
        }
        *(v8s*)((char*)vout + dd * 128 + ((bi ^ (dd & 7)) << 4)) = r.v;
    }
}

// ---------- attention v5b: 4 waves x 32 q-rows, 32x32x16 MFMA, in-lane softmax ----

__global__ __launch_bounds__(256, 2)
void attn_v5(const float* __restrict__ qg, const u16* __restrict__ wsK,
             const u16* __restrict__ wsV, float* __restrict__ outg) {
    __shared__ __align__(16) u16 KT[2][4096];
    __shared__ __align__(16) u16 VT[2][4096];

    const int bid  = blockIdx.x;
    const int wgid = (bid & 7) * 64 + (bid >> 3);   // XCD-contiguous (512 % 8 == 0)
    const int qt   = wgid & 15;
    const int hH   = (wgid >> 4) & 15;
    const int b    = wgid >> 8;
    const int tid  = threadIdx.x;
    const int lane = tid & 63;
    const int wid  = tid >> 6;
    const int al   = lane & 31;     // q-row (B col) / matrix row index
    const int hh   = lane >> 5;     // k-slot half

    const u16* kbase = wsK + (size_t)(b * 16 + hH) * 131072;
    const u16* vbase = wsV + (size_t)(b * 16 + hH) * 131072;

    const int q0 = qt * 128 + wid * 32;
    const int qr = q0 + al;          // this lane's q-row

    // Q fragments (pre-scaled into exp2 domain): qf[c] slots (j,hh) <-> d = 16c + M(j,hh)
    const float qscale = 0.125f * 1.4426950408889634f;
    v8s qf[4];
    {
        const float* qb = qg + ((size_t)((b * TT + qr) * HH + hH)) * DD;
        #pragma unroll
        for (int c = 0; c < 4; ++c) {
            float4 lo = *(const float4*)(qb + 16 * c + 4 * hh);
            float4 hi = *(const float4*)(qb + 16 * c + 4 * hh + 8);
            qf[c] = cvt8s(lo, hi, qscale);
        }
    }

#define STAGE(buf, tt)                                                                                    \
    do {                                                                                                  \
        gl_lds16(kbase + (size_t)(tt) * 4096 + tid * 8,        (char*)&KT[buf][0] + wid * 1024);          \
        gl_lds16(kbase + (size_t)(tt) * 4096 + 2048 + tid * 8, (char*)&KT[buf][0] + 4096 + wid * 1024);   \
        gl_lds16(vbase + (size_t)(tt) * 4096 + tid * 8,        (char*)&VT[buf][0] + wid * 1024);          \
        gl_lds16(vbase + (size_t)(tt) * 4096 + 2048 + tid * 8, (char*)&VT[buf][0] + 4096 + wid * 1024);   \
    } while (0)

    STAGE(0, 0);

    v16f oa[2];
    #pragma unroll
    for (int dt = 0; dt < 2; ++dt)
        #pragma unroll
        for (int r = 0; r < 16; ++r) oa[dt][r] = 0.0f;
    float m = -INFINITY, lsum = 0.0f;

    for (int t = 0; t < 32; ++t) {
        const int cur = t & 1;
        if (t < 31) {
            STAGE(cur ^ 1, t + 1);
            asm volatile("s_waitcnt vmcnt(4)" ::: "memory");
        } else {
            asm volatile("s_waitcnt vmcnt(0)" ::: "memory");
        }
        __builtin_amdgcn_s_barrier();

        const char* kb = (const char*)&KT[cur][0];
        const char* vb = (const char*)&VT[cur][0];

        // ---- QK^T (swapped): st[kt] = K(32kv x 64d) x Q^T; D col = q (lane&31),
        //      D row r <-> kv = 32kt + (r&3) + 8*(r>>2) + 4*hh  [HW C-layout m74/m101]
        v16f st[2];
        #pragma unroll
        for (int kt = 0; kt < 2; ++kt)
            #pragma unroll
            for (int r = 0; r < 16; ++r) st[kt][r] = 0.0f;
        __builtin_amdgcn_s_setprio(1);
        #pragma unroll
        for (int c = 0; c < 4; ++c) {
            #pragma unroll
            for (int kt = 0; kt < 2; ++kt) {
                int row = 32 * kt + al;
                v8s kf = *(const v8s*)(kb + row * 128 + (((2 * c + hh) ^ (row & 7)) << 4));
                st[kt] = __builtin_amdgcn_mfma_f32_32x32x16_bf16(kf, qf[c], st[kt], 0, 0, 0);
            }
        }
        __builtin_amdgcn_s_setprio(0);

        // ---- in-lane online softmax (lane owns q-row qr; lane^32 holds other kv half)
        float mc = st[0][0];
        #pragma unroll
        for (int kt = 0; kt < 2; ++kt)
            #pragma unroll
            for (int r = 0; r < 16; ++r) mc = fmaxf(mc, st[kt][r]);
        mc = fmaxf(mc, __shfl_xor(mc, 32));
        if (!__all(mc - m <= 8.0f)) {
            float mnew  = fmaxf(m, mc);
            float alpha = __builtin_amdgcn_exp2f(m - mnew);
            lsum *= alpha;
            m = mnew;
            #pragma unroll
            for (int dt = 0; dt < 2; ++dt)
                #pragma unroll
                for (int r = 0; r < 16; ++r) oa[dt][r] *= alpha;
        }
        float ps = 0.0f;
        #pragma unroll
        for (int kt = 0; kt < 2; ++kt)
            #pragma unroll
            for (int r = 0; r < 16; ++r) {
                float e = __builtin_amdgcn_exp2f(st[kt][r] - m);
                st[kt][r] = e;
                ps += e;
            }
        ps += __shfl_xor(ps, 32);
        lsum += ps;

        // ---- P -> bf16 B-frags: chunk cc uses st[cc>>1] regs 8*(cc&1)+0..7 ----
        v8s pf[4];
        #pragma unroll
        for (int cc = 0; cc < 4; ++cc) {
            const int kt = cc >> 1, u8 = 8 * (cc & 1);
            union { v8s v; unsigned u[4]; } r;
            #pragma unroll
            for (int w = 0; w < 4; ++w)
                r.u[w] = cvtpk(st[kt][u8 + 2 * w], st[kt][u8 + 2 * w + 1]);
            pf[cc] = r.v;
        }

        // ---- PV: O^T[d][q] += V^T x P^T ----
        __builtin_amdgcn_s_setprio(1);
        #pragma unroll
        for (int cc = 0; cc < 4; ++cc) {
            #pragma unroll
            for (int dt = 0; dt < 2; ++dt) {
                int row = 32 * dt + al;
                v8s vf = *(const v8s*)(vb + row * 128 + (((2 * cc + hh) ^ (row & 7)) << 4));
                oa[dt] = __builtin_amdgcn_mfma_f32_32x32x16_bf16(vf, pf[cc], oa[dt], 0, 0, 0);
            }
        }
        __builtin_amdgcn_s_setprio(0);

        __builtin_amdgcn_s_barrier();
    }

    // ---- epilogue: lane-local 1/lsum, store O^T fragment ----
    float rl = 1.0f / lsum;
    const size_t obase = ((size_t)((b * TT + qr) * HH + hH)) * DD;
    #pragma unroll
    for (int dt = 0; dt < 2; ++dt)
        #pragma unroll
        for (int r = 0; r < 16; ++r) {
            int d = 32 * dt + (r & 3) + 8 * (r >> 2) + 4 * hh;
            outg[obase + d] = oa[dt][r] * rl;
        }
}

// ---------- fallback v1 (proven, ws-independent) ----------

__global__ __launch_bounds__(256)
void attn_fwd_v1(const float* __restrict__ qg, const float* __restrict__ kvg,
                 float* __restrict__ outg) {
    __shared__ __align__(16) u16 Klds[32][68];
    __shared__ __align__(16) u16 Vt[DD][36];

    const int wg    = blockIdx.x;
    const int qtile = wg & 31;
    const int h     = (wg >> 5) & 15;
    const int b     = wg >> 9;
    const int tid   = threadIdx.x;
    const int lane  = tid & 63;
    const int wid   = tid >> 6;
    const int lr    = lane & 15;
    const int lg    = lane >> 4;
    const int q0    = qtile * 64 + wid * 16;

    const float qscale = 0.125f * 1.4426950408889634f;
    v8s qf[2];
    {
        const float* qb = qg + ((size_t)((b * TT + q0 + lr) * HH + h)) * DD;
        #pragma unroll
        for (int c = 0; c < 2; ++c) {
            float4 lo = *(const float4*)(qb + 32 * c + 4 * lg);
            float4 hi = *(const float4*)(qb + 32 * c + 4 * lg + 16);
            qf[c] = cvt8s(lo, hi, qscale);
        }
    }

    v4f oa[4];
    #pragma unroll
    for (int dc = 0; dc < 4; ++dc)
        #pragma unroll
        for (int r = 0; r < 4; ++r) oa[dc][r] = 0.0f;
    float m = -INFINITY, lsum = 0.0f;

    for (int kv0 = 0; kv0 < TT; kv0 += 32) {
        __syncthreads();
        #pragma unroll
        for (int i = 0; i < 2; ++i) {
            int id  = tid + 256 * i;
            int row = id >> 4;
            int cg  = (id & 15) * 4;
            const float* gp = kvg + ((size_t)(((b * TT + kv0 + row) * 2 + 0) * HH + h)) * DD + cg;
            float4 f = *(const float4*)gp;
            ushort4 w;
            w.x = f2bf(f.x); w.y = f2bf(f.y); w.z = f2bf(f.z); w.w = f2bf(f.w);
            *(ushort4*)&Klds[row][cg] = w;
        }
        {
            int s0 = tid >> 4;
            int dg = (tid & 15) * 4;
            const float* gp0 = kvg + ((size_t)(((b * TT + kv0 + 2 * s0) * 2 + 1) * HH + h)) * DD + dg;
            const float* gp1 = gp0 + 2 * HH * DD;
            float4 fa = *(const float4*)gp0;
            float4 fb = *(const float4*)gp1;
            float av[4] = {fa.x, fa.y, fa.z, fa.w};
            float bv[4] = {fb.x, fb.y, fb.z, fb.w};
            #pragma unroll
            for (int i = 0; i < 4; ++i) {
                ushort2 w;
                w.x = f2bf(av[i]);
                w.y = f2bf(bv[i]);
                *(ushort2*)&Vt[dg + i][2 * s0] = w;
            }
        }
        __syncthreads();

        v4f st0, st1;
        #pragma unroll
        for (int r = 0; r < 4; ++r) { st0[r] = 0.0f; st1[r] = 0.0f; }
        #pragma unroll
        for (int c = 0; c < 2; ++c) {
            {
                u64 lo = *(const u64*)&Klds[lr][32 * c + 4 * lg];
                u64 hi = *(const u64*)&Klds[lr][32 * c + 4 * lg + 16];
                st0 = __builtin_amdgcn_mfma_f32_16x16x32_bf16(pack8(lo, hi), qf[c], st0, 0, 0, 0);
            }
            {
                u64 lo = *(const u64*)&Klds[16 + lr][32 * c + 4 * lg];
                u64 hi = *(const u64*)&Klds[16 + lr][32 * c + 4 * lg + 16];
                st1 = __builtin_amdgcn_mfma_f32_16x16x32_bf16(pack8(lo, hi), qf[c], st1, 0, 0, 0);
            }
        }

        float sc[8] = {st0[0], st0[1], st0[2], st0[3], st1[0], st1[1], st1[2], st1[3]};
        float mc = sc[0];
        #pragma unroll
        for (int i = 1; i < 8; ++i) mc = fmaxf(mc, sc[i]);
        mc = fmaxf(mc, __shfl_xor(mc, 16));
        mc = fmaxf(mc, __shfl_xor(mc, 32));
        float mnew  = fmaxf(m, mc);
        float alpha = __builtin_amdgcn_exp2f(m - mnew);
        float p[8], ps = 0.0f;
        #pragma unroll
        for (int i = 0; i < 8; ++i) { p[i] = __builtin_amdgcn_exp2f(sc[i] - mnew); ps += p[i]; }
        ps += __shfl_xor(ps, 16);
        ps += __shfl_xor(ps, 32);
        lsum = lsum * alpha + ps;
        m = mnew;

        float ar0 = __shfl(alpha, 4 * lg + 0);
        float ar1 = __shfl(alpha, 4 * lg + 1);
        float ar2 = __shfl(alpha, 4 * lg + 2);
        float ar3 = __shfl(alpha, 4 * lg + 3);
        #pragma unroll
        for (int dc = 0; dc < 4; ++dc) {
            oa[dc][0] *= ar0; oa[dc][1] *= ar1; oa[dc][2] *= ar2; oa[dc][3] *= ar3;
        }

        v8s pf;
        #pragma unroll
        for (int i = 0; i < 8; ++i) pf[i] = (short)f2bf(p[i]);

        #pragma unroll
        for (int dc = 0; dc < 4; ++dc) {
            u64 lo = *(const u64*)&Vt[16 * dc + lr][4 * lg];
            u64 hi = *(const u64*)&Vt[16 * dc + lr][4 * lg + 16];
            oa[dc] = __builtin_amdgcn_mfma_f32_16x16x32_bf16(pf, pack8(lo, hi), oa[dc], 0, 0, 0);
        }
    }

    float rl  = 1.0f / lsum;
    float rr0 = __shfl(rl, 4 * lg + 0);
    float rr1 = __shfl(rl, 4 * lg + 1);
    float rr2 = __shfl(rl, 4 * lg + 2);
    float rr3 = __shfl(rl, 4 * lg + 3);
    #pragma unroll
    for (int dc = 0; dc < 4; ++dc) {
        size_t base = ((size_t)((b * TT + q0) * HH + h)) * DD + 16 * dc + lr;
        outg[base + (size_t)(4 * lg + 0) * HH * DD] = oa[dc][0] * rr0;
        outg[base + (size_t)(4 * lg + 1) * HH * DD] = oa[dc][1] * rr1;
        outg[base + (size_t)(4 * lg + 2) * HH * DD] = oa[dc][2] * rr2;
        outg[base + (size_t)(4 * lg + 3) * HH * DD] = oa[dc][3] * rr3;
    }
}

extern "C" void kernel_launch(void* const* d_in, const int* in_sizes, int n_in,
                              void* d_out, int out_size, void* d_ws, size_t ws_size,
                              hipStream_t stream) {
    const float* q  = (const float*)d_in[0];
    const float* kv = (const float*)d_in[1];
    float* out      = (float*)d_out;
    if (ws_size >= (size_t)16777216) {
        u16* wsK = (u16*)d_ws;
        u16* wsV = wsK + 4194304;
        hipLaunchKernelGGL(prep_kv, dim3(BB * HH * 32), dim3(256), 0, stream, kv, wsK, wsV);
        hipLaunchKernelGGL(attn_v5, dim3(512), dim3(256), 0, stream, q, wsK, wsV, out);
    } else {
        hipLaunchKernelGGL(attn_fwd_v1, dim3(1024), dim3(256), 0, stream, q, kv, out);
    }
}